// Round 9
// baseline (170.064 us; speedup 1.0000x reference)
//
#include <hip/hip_runtime.h>
#include <math.h>

#define C 128  // IN_C == OUT_C == 128

typedef _Float16 f16x8 __attribute__((ext_vector_type(8)));
typedef __attribute__((ext_vector_type(4))) float f32x4;

static __device__ __forceinline__ unsigned int pkh2(float lo, float hi) {
    unsigned short l = __builtin_bit_cast(unsigned short, (_Float16)lo);
    unsigned short h = __builtin_bit_cast(unsigned short, (_Float16)hi);
    return ((unsigned int)h << 16) | l;
}
static __device__ __forceinline__ float h2f_lo(unsigned int u) {
    return (float)__builtin_bit_cast(_Float16, (unsigned short)(u & 0xFFFFu));
}
static __device__ __forceinline__ float h2f_hi(unsigned int u) {
    return (float)__builtin_bit_cast(_Float16, (unsigned short)(u >> 16));
}
static __device__ __forceinline__ int dot4i8(unsigned int a, unsigned int b, int c) {
#if __has_builtin(__builtin_amdgcn_sdot4)
    return __builtin_amdgcn_sdot4(a, b, c, false);
#else
    c += (int)(signed char)(a & 0xff)         * (int)(signed char)(b & 0xff);
    c += (int)(signed char)((a >> 8) & 0xff)  * (int)(signed char)((b >> 8) & 0xff);
    c += (int)(signed char)((a >> 16) & 0xff) * (int)(signed char)((b >> 16) & 0xff);
    c += (int)(signed char)((a >> 24) & 0xff) * (int)(signed char)((b >> 24) & 0xff);
    return c;
#endif
}

// ---------------------------------------------------------------------------
// K_pre: fused [bin histogram] + [emb absmax reduction]
// ---------------------------------------------------------------------------
__global__ __launch_bounds__(256) void k_pre(const int* __restrict__ eidx,
                                             int* __restrict__ binCounts,
                                             const uint4* __restrict__ embv,
                                             int* __restrict__ amax,
                                             int E, int total4, int nEdgeBlocks) {
    __shared__ int lsh[256];
    const int t = threadIdx.x;
    if ((int)blockIdx.x < nEdgeBlocks) {
        lsh[t] = 0;
        __syncthreads();
        const int base = blockIdx.x * 2048;
#pragma unroll
        for (int j = 0; j < 8; ++j) {
            const int e = base + j * 256 + t;
            if (e < E) atomicAdd(&lsh[eidx[E + e] >> 8], 1);
        }
        __syncthreads();
        const int v = lsh[t];
        if (v) atomicAdd(&binCounts[t], v);
    } else {
        const int b = blockIdx.x - nEdgeBlocks;
        const int stride = ((int)gridDim.x - nEdgeBlocks) * 256;
        int m = 0;
        for (int i = b * 256 + t; i < total4; i += stride) {
            const uint4 v = embv[i];
            m = max(m, (int)(v.x & 0x7fffffffu));
            m = max(m, (int)(v.y & 0x7fffffffu));
            m = max(m, (int)(v.z & 0x7fffffffu));
            m = max(m, (int)(v.w & 0x7fffffffu));
        }
        lsh[t] = m;
        __syncthreads();
        for (int o = 128; o > 0; o >>= 1) {
            if (t < o) lsh[t] = max(lsh[t], lsh[t + o]);
            __syncthreads();
        }
        if (t == 0) atomicMax(amax, lsh[0]);   // positive-float-as-int compare
    }
}

// ---------------------------------------------------------------------------
// K0: emb f32 -> i8 (scale 126/absmax, never clamps) + per-row L1 norm (i8
// units, u16); W f32 -> f16. One thread = 8 elems. NOTE: emb region is an
// exact multiple of 256 threads (N*16), so no block mixes branches (shfl ok).
// ---------------------------------------------------------------------------
__global__ __launch_bounds__(256) void k_cast(const float* __restrict__ embf,
                                              unsigned int* __restrict__ embq,
                                              unsigned short* __restrict__ n1q,
                                              const float* __restrict__ Wf,
                                              unsigned int* __restrict__ Wh,
                                              const int* __restrict__ amax,
                                              int totalA8, int totalB8) {
    const int t = threadIdx.x;
    int i = blockIdx.x * 256 + t;
    if (i < totalA8) {
        const float s = 126.0f / fmaxf(__int_as_float(*amax), 1e-20f);
        const float4 a = ((const float4*)embf)[i * 2];
        const float4 b = ((const float4*)embf)[i * 2 + 1];
        int q[8];
        q[0] = __float2int_rn(a.x * s); q[1] = __float2int_rn(a.y * s);
        q[2] = __float2int_rn(a.z * s); q[3] = __float2int_rn(a.w * s);
        q[4] = __float2int_rn(b.x * s); q[5] = __float2int_rn(b.y * s);
        q[6] = __float2int_rn(b.z * s); q[7] = __float2int_rn(b.w * s);
        uint2 o;
        o.x = (unsigned)(q[0] & 255) | ((unsigned)(q[1] & 255) << 8) |
              ((unsigned)(q[2] & 255) << 16) | ((unsigned)(q[3] & 255) << 24);
        o.y = (unsigned)(q[4] & 255) | ((unsigned)(q[5] & 255) << 8) |
              ((unsigned)(q[6] & 255) << 16) | ((unsigned)(q[7] & 255) << 24);
        ((uint2*)embq)[i] = o;
        int n1 = abs(q[0]) + abs(q[1]) + abs(q[2]) + abs(q[3]) +
                 abs(q[4]) + abs(q[5]) + abs(q[6]) + abs(q[7]);
#pragma unroll
        for (int o2 = 1; o2 < 16; o2 <<= 1) n1 += __shfl_xor(n1, o2);
        if ((t & 15) == 0) n1q[i >> 4] = (unsigned short)n1;
    } else {
        i -= totalA8;
        if (i >= totalB8) return;
        const float4 a = ((const float4*)Wf)[i * 2];
        const float4 b = ((const float4*)Wf)[i * 2 + 1];
        uint4 o;
        o.x = pkh2(a.x, a.y); o.y = pkh2(a.z, a.w);
        o.z = pkh2(b.x, b.y); o.w = pkh2(b.z, b.w);
        ((uint4*)Wh)[i] = o;
    }
}

// ---------------------------------------------------------------------------
// K1: xl = x @ W^T via MFMA f16. Block = 4 waves, 64 rows (16/wave).
// ---------------------------------------------------------------------------
__global__ __launch_bounds__(256) void k_gemm(const float* __restrict__ x,
                                              const uint4* __restrict__ wb,
                                              unsigned short* __restrict__ xlh, int N) {
    const int lane = threadIdx.x & 63;
    const int wave = threadIdx.x >> 6;
    const int row0 = blockIdx.x * 64 + wave * 16;
    const int r = lane & 15, kg = lane >> 4;

    int arow = row0 + r;
    if (arow >= N) arow = N - 1;          // clamp (stores are guarded)
    const float* xrow = x + (size_t)arow * C;
    f16x8 A[4];
#pragma unroll
    for (int kb = 0; kb < 4; ++kb) {
        const float4 p0 = ((const float4*)(xrow + kb * 32 + kg * 8))[0];
        const float4 p1 = ((const float4*)(xrow + kb * 32 + kg * 8))[1];
        f16x8 a;
        a[0] = (_Float16)p0.x; a[1] = (_Float16)p0.y;
        a[2] = (_Float16)p0.z; a[3] = (_Float16)p0.w;
        a[4] = (_Float16)p1.x; a[5] = (_Float16)p1.y;
        a[6] = (_Float16)p1.z; a[7] = (_Float16)p1.w;
        A[kb] = a;
    }

#pragma unroll
    for (int nt = 0; nt < 8; ++nt) {
        const uint4* wrow = wb + (size_t)(nt * 16 + r) * 16;
        f32x4 acc = {0.0f, 0.0f, 0.0f, 0.0f};
#pragma unroll
        for (int kb = 0; kb < 4; ++kb) {
            f16x8 B = __builtin_bit_cast(f16x8, wrow[kb * 4 + kg]);
            acc = __builtin_amdgcn_mfma_f32_16x16x32_f16(A[kb], B, acc, 0, 0, 0);
        }
        const int orow = row0 + kg * 4;
        const int ocol = nt * 16 + r;
#pragma unroll
        for (int i = 0; i < 4; ++i)
            if (orow + i < N)
                xlh[(size_t)(orow + i) * C + ocol] =
                    __builtin_bit_cast(unsigned short, (_Float16)acc[i]);
    }
}

// ---------------------------------------------------------------------------
// CSR build (bucket sort). Record u32: [31:24]=dst&255, [23:0]=src.
// ---------------------------------------------------------------------------
__global__ __launch_bounds__(256) void k_binscan(const int* __restrict__ binCounts,
                                                 int* __restrict__ binOffs,
                                                 int* __restrict__ binCursor, int NB) {
    __shared__ int ts[256];
    const int t = threadIdx.x;
    const int v = (t < NB) ? binCounts[t] : 0;
    ts[t] = v;
    __syncthreads();
    for (int o = 1; o < 256; o <<= 1) {
        int u = (t >= o) ? ts[t - o] : 0;
        __syncthreads();
        ts[t] += u;
        __syncthreads();
    }
    const int excl = ts[t] - v;
    if (t <= NB) binOffs[t] = excl;     // binOffs[NB] = E
    if (t < NB) binCursor[t] = excl;
}

__global__ __launch_bounds__(256) void k_bin(const int* __restrict__ eidx,
                                             int* __restrict__ binCursor,
                                             unsigned int* __restrict__ binned, int E) {
    __shared__ int lh[256];
    __shared__ int lb[256];
    const int t = threadIdx.x;
    lh[t] = 0;
    __syncthreads();
    const int base = blockIdx.x * 2048;
    int bj[8], rj[8];
    unsigned int recj[8];
#pragma unroll
    for (int j = 0; j < 8; ++j) {
        const int e = base + j * 256 + t;
        bj[j] = -1;
        if (e < E) {
            const int s = eidx[e];
            const int d = eidx[E + e];
            bj[j] = d >> 8;
            recj[j] = ((unsigned)(d & 255) << 24) | (unsigned)s;
            rj[j] = atomicAdd(&lh[bj[j]], 1);
        }
    }
    __syncthreads();
    const int c = lh[t];
    if (c) lb[t] = atomicAdd(&binCursor[t], c);
    __syncthreads();
#pragma unroll
    for (int j = 0; j < 8; ++j) {
        if (bj[j] >= 0) binned[lb[bj[j]] + rj[j]] = recj[j];
    }
}

__global__ __launch_bounds__(256) void k_place(const unsigned int* __restrict__ binned,
                                               const int* __restrict__ binOffs,
                                               int* __restrict__ offs,
                                               int* __restrict__ src_s,
                                               int N, int E) {
    __shared__ int cnt[256];
    __shared__ int ts[256];
    __shared__ int cur[256];
    const int b = blockIdx.x;
    const int t = threadIdx.x;
    const int node0 = b * 256;
    const int r0 = binOffs[b], r1 = binOffs[b + 1];
    cnt[t] = 0;
    __syncthreads();
    for (int i = r0 + t; i < r1; i += 256)
        atomicAdd(&cnt[binned[i] >> 24], 1);
    __syncthreads();
    const int v = cnt[t];
    ts[t] = v;
    __syncthreads();
    for (int o = 1; o < 256; o <<= 1) {
        int u = (t >= o) ? ts[t - o] : 0;
        __syncthreads();
        ts[t] += u;
        __syncthreads();
    }
    const int excl = r0 + ts[t] - v;
    if (node0 + t < N) offs[node0 + t] = excl;
    cur[t] = excl;
    __syncthreads();
    for (int i = r0 + t; i < r1; i += 256) {
        const unsigned int rec = binned[i];
        const int pos = atomicAdd(&cur[rec >> 24], 1);
        src_s[pos] = (int)(rec & 0xFFFFFFu);
    }
    if (b == 0 && t == 0) offs[N] = E;
}

// ---------------------------------------------------------------------------
// K4: fused attention + deferred-max online softmax + aggregation.
// One wave per node, 8 edges/iter. Common path: i8 dot (4x v_dot4 per lane,
// 128B/edge gather) + per-group denominator partials (1 exp / 8 lanes).
// Certificate: alpha_i8 error <= q^2*(0.5*(n1[d]+n1[s])+96); edges with
// alpha+delta > m-30 take the exact f32 path (gather emb row, exact dot,
// max update, xl gather if w>1e-12). Error from skipped terms < e^-30*deg.
// ---------------------------------------------------------------------------
__global__ __launch_bounds__(256) void k_agg(const unsigned int* __restrict__ xlh,
                                             const float* __restrict__ emb,
                                             const uint4* __restrict__ embq4,
                                             const unsigned short* __restrict__ n1q,
                                             const int* __restrict__ src_s,
                                             const int* __restrict__ offs,
                                             const float* __restrict__ bias,
                                             const int* __restrict__ amax,
                                             float* __restrict__ out, int N) {
    const int node = (int)((blockIdx.x * (size_t)blockDim.x + threadIdx.x) >> 6);
    const int lane = threadIdx.x & 63;
    if (node >= N) return;
    const int g = lane >> 3;        // edge slot 0..7
    const int sl = lane & 7;        // sub-lane within 8-group
    const int s0 = offs[node], s1 = offs[node + 1];

    const float maxabs = fmaxf(__int_as_float(*amax), 1e-20f);
    const float qs = maxabs / 126.0f;
    const float q2 = qs * qs;

    // f32 emb row (exact side): 16 elems per lane covering [sl*16, sl*16+16)
    float ef[16];
    const float4* er = (const float4*)(emb + (size_t)node * C) + sl * 4;
#pragma unroll
    for (int k = 0; k < 4; ++k) {
        const float4 v = er[k];
        ef[k * 4 + 0] = v.x; ef[k * 4 + 1] = v.y;
        ef[k * 4 + 2] = v.z; ef[k * 4 + 3] = v.w;
    }
    // i8 row (16 i8 per lane) + L1 norm
    const uint4 qd = embq4[(size_t)node * 8 + sl];
    const int n1d = n1q[node];

    // exact self logit = ||emb||^2
    float p = 0.0f;
#pragma unroll
    for (int k = 0; k < 16; ++k) p = fmaf(ef[k], ef[k], p);
    p += __shfl_xor(p, 4); p += __shfl_xor(p, 2); p += __shfl_xor(p, 1);

    float m = p;                 // running max (self included, exact)
    float wself = 1.0f;          // exp(self - m)
    float dpart = 0.0f;          // per-group denominator partial
    float dex = 0.0f;            // exact-path denominator (wave-uniform)
    const unsigned int xw = xlh[(size_t)node * (C / 2) + lane];
    float2 acc = {h2f_lo(xw), h2f_hi(xw)};   // wself * xl[node]

    for (int base = s0; base < s1; base += 8) {
        int mys = -1, n1l = 0;
        if (lane < 8 && base + lane < s1) {
            mys = src_s[base + lane];
            n1l = n1q[mys];
        }
        const int sg = __shfl(mys, g);
        const int n1s = __shfl(n1l, g);
        const int sa = (sg >= 0) ? sg : node;

        const uint4 qv = embq4[(size_t)sa * 8 + sl];
        int ai = dot4i8(qv.x, qd.x, 0);
        ai = dot4i8(qv.y, qd.y, ai);
        ai = dot4i8(qv.z, qd.z, ai);
        ai = dot4i8(qv.w, qd.w, ai);
        ai += __shfl_xor(ai, 4); ai += __shfl_xor(ai, 2); ai += __shfl_xor(ai, 1);
        const float af = (float)ai * q2;
        const float delta = q2 * (0.5f * (float)(n1d + n1s) + 96.0f);
        const bool valid = sg >= 0;
        const bool trig = valid && (af + delta > m - 30.0f);

        if (__any(trig)) {
            const unsigned long long bal = __ballot(trig);
#pragma unroll 1
            for (int j = 0; j < 8; ++j) {
                if (!((bal >> (j * 8)) & 1ULL)) continue;
                const int sj = __shfl(mys, j);
                const float4* vr = (const float4*)(emb + (size_t)sj * C) + sl * 4;
                float ax = 0.0f;
#pragma unroll
                for (int k = 0; k < 4; ++k) {
                    const float4 v = vr[k];
                    ax = fmaf(ef[k * 4 + 0], v.x, ax);
                    ax = fmaf(ef[k * 4 + 1], v.y, ax);
                    ax = fmaf(ef[k * 4 + 2], v.z, ax);
                    ax = fmaf(ef[k * 4 + 3], v.w, ax);
                }
                ax += __shfl_xor(ax, 4); ax += __shfl_xor(ax, 2); ax += __shfl_xor(ax, 1);
                if (ax > m) {            // wave-uniform rescale
                    const float cs = __expf(m - ax);
                    dpart *= cs; dex *= cs; wself *= cs;
                    acc.x *= cs; acc.y *= cs;
                    m = ax;
                }
                const float w = __expf(ax - m);
                dex += w;
                if (w > 1e-12f) {
                    const unsigned int u = xlh[(size_t)sj * (C / 2) + lane];
                    acc.x = fmaf(w, h2f_lo(u), acc.x);
                    acc.y = fmaf(w, h2f_hi(u), acc.y);
                }
            }
        }
        dpart += (valid && !trig) ? __expf(af - m) : 0.0f;
    }

    // sum group partials (lanes within a group hold identical dpart)
    float dg = dpart;
    dg += __shfl_xor(dg, 8); dg += __shfl_xor(dg, 16); dg += __shfl_xor(dg, 32);
    const float dtot = wself + dex + dg;
    const float inv = 1.0f / (dtot + 1e-16f);
    const int c = lane * 2;
    float2 o2;
    o2.x = fmaf(acc.x, inv, bias[c]);
    o2.y = fmaf(acc.y, inv, bias[c + 1]);
    ((float2*)(out + (size_t)node * C))[lane] = o2;
}

// ---------------------------------------------------------------------------
// K5: BN stats — grid-stride float4; fixed channel quad per thread.
// ---------------------------------------------------------------------------
__global__ __launch_bounds__(256) void k_bnstats(const float* __restrict__ out,
                                                 float* __restrict__ ssum,
                                                 float* __restrict__ ssq, int N) {
    const int tid = threadIdx.x;
    const int total4 = N * (C / 4);
    const int stride = gridDim.x * 256;          // multiple of 32
    float4 s4 = {0, 0, 0, 0}, q4 = {0, 0, 0, 0};
    for (int i = blockIdx.x * 256 + tid; i < total4; i += stride) {
        float4 v = ((const float4*)out)[i];
        s4.x += v.x; s4.y += v.y; s4.z += v.z; s4.w += v.w;
        q4.x = fmaf(v.x, v.x, q4.x); q4.y = fmaf(v.y, v.y, q4.y);
        q4.z = fmaf(v.z, v.z, q4.z); q4.w = fmaf(v.w, v.w, q4.w);
    }
    __shared__ float4 lsum[256];
    __shared__ float4 lsq[256];
    lsum[tid] = s4; lsq[tid] = q4;
    __syncthreads();
    if (tid < 32) {
        float4 S = lsum[tid], Q = lsq[tid];
#pragma unroll
        for (int j = 1; j < 8; ++j) {
            float4 a = lsum[tid + 32 * j], b = lsq[tid + 32 * j];
            S.x += a.x; S.y += a.y; S.z += a.z; S.w += a.w;
            Q.x += b.x; Q.y += b.y; Q.z += b.z; Q.w += b.w;
        }
        const int c = tid * 4;
        atomicAdd(&ssum[c], S.x);     atomicAdd(&ssum[c + 1], S.y);
        atomicAdd(&ssum[c + 2], S.z); atomicAdd(&ssum[c + 3], S.w);
        atomicAdd(&ssq[c], Q.x);      atomicAdd(&ssq[c + 1], Q.y);
        atomicAdd(&ssq[c + 2], Q.z);  atomicAdd(&ssq[c + 3], Q.w);
    }
}

// ---------------------------------------------------------------------------
// K6: in-place BN apply (training-mode batch stats, biased var) + ReLU
// ---------------------------------------------------------------------------
__global__ __launch_bounds__(256) void k_bnapply(float* __restrict__ out,
                                                 const float* __restrict__ ssum,
                                                 const float* __restrict__ ssq,
                                                 const float* __restrict__ gamma,
                                                 const float* __restrict__ beta,
                                                 int N) {
    const int idx = blockIdx.x * blockDim.x + threadIdx.x;   // float4 index
    const int total = N * (C / 4);
    if (idx >= total) return;
    const int c = (idx * 4) & 127;
    float4 v = ((const float4*)out)[idx];
    const float invN = 1.0f / (float)N;
    float r[4] = {v.x, v.y, v.z, v.w};
#pragma unroll
    for (int j = 0; j < 4; ++j) {
        float mu = ssum[c + j] * invN;
        float var = fmaf(-mu, mu, ssq[c + j] * invN);
        var = fmaxf(var, 0.0f);
        float sc = gamma[c + j] / sqrtf(var + 1e-5f);
        float val = fmaf(r[j] - mu, sc, beta[c + j]);
        r[j] = fmaxf(val, 0.0f);
    }
    float4 o = {r[0], r[1], r[2], r[3]};
    ((float4*)out)[idx] = o;
}

// ---------------------------------------------------------------------------
extern "C" void kernel_launch(void* const* d_in, const int* in_sizes, int n_in,
                              void* d_out, int out_size, void* d_ws, size_t ws_size,
                              hipStream_t stream) {
    const float* x     = (const float*)d_in[0];
    const int*   eidx  = (const int*)d_in[1];   // [2][E]
    const float* emb   = (const float*)d_in[2];
    const float* W     = (const float*)d_in[3];
    const float* bias  = (const float*)d_in[4];
    const float* gamma = (const float*)d_in[5];
    const float* beta  = (const float*)d_in[6];
    const int N = in_sizes[0] / C;
    const int E = in_sizes[1] / 2;
    float* out = (float*)d_out;

    char* ws = (char*)d_ws;
    size_t off = 0;
    auto alloc = [&](size_t bytes) -> void* {
        void* p = ws + off;
        off = (off + bytes + 255) & ~(size_t)255;
        return p;
    };
    unsigned short* xlh  = (unsigned short*)alloc((size_t)N * C * 2);
    unsigned int*   embq = (unsigned int*)  alloc((size_t)N * C);       // i8
    unsigned short* n1q  = (unsigned short*)alloc((size_t)N * 2);
    unsigned int*   wh   = (unsigned int*)  alloc((size_t)C * C * 2);
    int*   src_s    = (int*)  alloc((size_t)E * 4);
    unsigned int* binned = (unsigned int*)alloc((size_t)E * 4);
    int*   offs     = (int*)  alloc((size_t)(N + 1) * 4);
    int*   binOffs  = (int*)  alloc(257 * 4);
    int*   binCur   = (int*)  alloc(256 * 4);
    // contiguous zero-init region: binCounts + amax + ssum + ssq
    char*  zbase    = (char*)alloc(0);
    int*   binCounts= (int*)  alloc(256 * 4);
    int*   amax     = (int*)  alloc(4);
    float* ssum     = (float*)alloc(C * 4);
    float* ssq      = (float*)alloc(C * 4);
    size_t zbytes   = (char*)ws + off - zbase;

    const int NB = (N + 255) / 256;              // 196 bins (<= 255)
    const int nEdgeBlocks = (E + 2047) / 2048;   // 391
    const int embTot8 = N * (C / 8);             // multiple of 256 (N=50000)
    const int wTot8   = C * (C / 8);
    const int embTot4 = N * (C / 4);

    hipMemsetAsync(zbase, 0, zbytes, stream);

    k_pre    <<<nEdgeBlocks + 256, 256, 0, stream>>>(
                 eidx, binCounts, (const uint4*)emb, amax, E, embTot4, nEdgeBlocks);
    k_cast   <<<(embTot8 + wTot8 + 255) / 256, 256, 0, stream>>>(
                 emb, embq, n1q, W, wh, amax, embTot8, wTot8);
    k_gemm   <<<(N + 63) / 64,   256, 0, stream>>>(x, (const uint4*)wh, xlh, N);
    k_binscan<<<1,               256, 0, stream>>>(binCounts, binOffs, binCur, NB);
    k_bin    <<<nEdgeBlocks,     256, 0, stream>>>(eidx, binCur, binned, E);
    k_place  <<<NB,              256, 0, stream>>>(binned, binOffs, offs, src_s, N, E);
    k_agg    <<<(int)(((size_t)N * 64 + 255) / 256), 256, 0, stream>>>(
                 (const unsigned int*)xlh, emb, (const uint4*)embq, n1q,
                 src_s, offs, bias, amax, out, N);
    k_bnstats<<<256,             256, 0, stream>>>(out, ssum, ssq, N);
    k_bnapply<<<(N * (C / 4) + 255) / 256, 256, 0, stream>>>(out, ssum, ssq, gamma, beta, N);
}

// Round 10
// 153.223 us; speedup vs baseline: 1.1099x; 1.1099x over previous
//
#include <hip/hip_runtime.h>
#include <math.h>

#define C 128  // IN_C == OUT_C == 128

typedef _Float16 f16x8 __attribute__((ext_vector_type(8)));
typedef _Float16 half2_t __attribute__((ext_vector_type(2)));
typedef __attribute__((ext_vector_type(4))) float f32x4;

static __device__ __forceinline__ unsigned int pkh2(float lo, float hi) {
    unsigned short l = __builtin_bit_cast(unsigned short, (_Float16)lo);
    unsigned short h = __builtin_bit_cast(unsigned short, (_Float16)hi);
    return ((unsigned int)h << 16) | l;
}
static __device__ __forceinline__ float h2f_lo(unsigned int u) {
    return (float)__builtin_bit_cast(_Float16, (unsigned short)(u & 0xFFFFu));
}
static __device__ __forceinline__ float h2f_hi(unsigned int u) {
    return (float)__builtin_bit_cast(_Float16, (unsigned short)(u >> 16));
}
static __device__ __forceinline__ float dot2acc(unsigned int a, unsigned int b, float c) {
#if __has_builtin(__builtin_amdgcn_fdot2)
    return __builtin_amdgcn_fdot2(__builtin_bit_cast(half2_t, a),
                                  __builtin_bit_cast(half2_t, b), c, false);
#else
    c = fmaf(h2f_lo(a), h2f_lo(b), c);
    return fmaf(h2f_hi(a), h2f_hi(b), c);
#endif
}

// ---------------------------------------------------------------------------
// K0: f32 -> packed f16 for emb and W. One thread = 8 elems.
// ---------------------------------------------------------------------------
__global__ __launch_bounds__(256) void k_cast(const float* __restrict__ embf,
                                              unsigned int* __restrict__ embh,
                                              const float* __restrict__ Wf,
                                              unsigned int* __restrict__ Wh,
                                              int totalA8, int totalB8) {
    int i = blockIdx.x * 256 + threadIdx.x;
    const float* in;
    unsigned int* outp;
    if (i < totalA8) {
        in = embf; outp = embh;
    } else {
        i -= totalA8;
        if (i >= totalB8) return;
        in = Wf; outp = Wh;
    }
    const float4 a = ((const float4*)in)[i * 2];
    const float4 b = ((const float4*)in)[i * 2 + 1];
    uint4 o;
    o.x = pkh2(a.x, a.y); o.y = pkh2(a.z, a.w);
    o.z = pkh2(b.x, b.y); o.w = pkh2(b.z, b.w);
    ((uint4*)outp)[i] = o;
}

// ---------------------------------------------------------------------------
// K1: xl = x @ W^T via MFMA f16. Block = 4 waves, 64 rows (16/wave).
// ---------------------------------------------------------------------------
__global__ __launch_bounds__(256) void k_gemm(const float* __restrict__ x,
                                              const uint4* __restrict__ wb,
                                              unsigned short* __restrict__ xlh, int N) {
    const int lane = threadIdx.x & 63;
    const int wave = threadIdx.x >> 6;
    const int row0 = blockIdx.x * 64 + wave * 16;
    const int r = lane & 15, kg = lane >> 4;

    int arow = row0 + r;
    if (arow >= N) arow = N - 1;          // clamp (stores are guarded)
    const float* xrow = x + (size_t)arow * C;
    f16x8 A[4];
#pragma unroll
    for (int kb = 0; kb < 4; ++kb) {
        const float4 p0 = ((const float4*)(xrow + kb * 32 + kg * 8))[0];
        const float4 p1 = ((const float4*)(xrow + kb * 32 + kg * 8))[1];
        f16x8 a;
        a[0] = (_Float16)p0.x; a[1] = (_Float16)p0.y;
        a[2] = (_Float16)p0.z; a[3] = (_Float16)p0.w;
        a[4] = (_Float16)p1.x; a[5] = (_Float16)p1.y;
        a[6] = (_Float16)p1.z; a[7] = (_Float16)p1.w;
        A[kb] = a;
    }

#pragma unroll
    for (int nt = 0; nt < 8; ++nt) {
        const uint4* wrow = wb + (size_t)(nt * 16 + r) * 16;
        f32x4 acc = {0.0f, 0.0f, 0.0f, 0.0f};
#pragma unroll
        for (int kb = 0; kb < 4; ++kb) {
            f16x8 B = __builtin_bit_cast(f16x8, wrow[kb * 4 + kg]);
            acc = __builtin_amdgcn_mfma_f32_16x16x32_f16(A[kb], B, acc, 0, 0, 0);
        }
        const int orow = row0 + kg * 4;
        const int ocol = nt * 16 + r;
#pragma unroll
        for (int i = 0; i < 4; ++i)
            if (orow + i < N)
                xlh[(size_t)(orow + i) * C + ocol] =
                    __builtin_bit_cast(unsigned short, (_Float16)acc[i]);
    }
}

// ---------------------------------------------------------------------------
// CSR build (bucket sort). Bin = dst>>8. Record u32: [31:24]=dst&255,
// [23:0]=src (needs N < 2^24).
// ---------------------------------------------------------------------------
__global__ __launch_bounds__(256) void k_binhist(const int* __restrict__ eidx,
                                                 int* __restrict__ binCounts, int E) {
    __shared__ int lh[256];
    const int t = threadIdx.x;
    lh[t] = 0;
    __syncthreads();
    const int base = blockIdx.x * 2048;
#pragma unroll
    for (int j = 0; j < 8; ++j) {
        const int e = base + j * 256 + t;
        if (e < E) atomicAdd(&lh[eidx[E + e] >> 8], 1);
    }
    __syncthreads();
    const int v = lh[t];
    if (v) atomicAdd(&binCounts[t], v);
}

__global__ __launch_bounds__(256) void k_binscan(const int* __restrict__ binCounts,
                                                 int* __restrict__ binOffs,
                                                 int* __restrict__ binCursor, int NB) {
    __shared__ int ts[256];
    const int t = threadIdx.x;
    const int v = (t < NB) ? binCounts[t] : 0;
    ts[t] = v;
    __syncthreads();
    for (int o = 1; o < 256; o <<= 1) {
        int u = (t >= o) ? ts[t - o] : 0;
        __syncthreads();
        ts[t] += u;
        __syncthreads();
    }
    const int excl = ts[t] - v;
    if (t <= NB) binOffs[t] = excl;     // binOffs[NB] = E
    if (t < NB) binCursor[t] = excl;
}

__global__ __launch_bounds__(256) void k_bin(const int* __restrict__ eidx,
                                             int* __restrict__ binCursor,
                                             unsigned int* __restrict__ binned, int E) {
    __shared__ int lh[256];
    __shared__ int lb[256];
    const int t = threadIdx.x;
    lh[t] = 0;
    __syncthreads();
    const int base = blockIdx.x * 2048;
    int bj[8], rj[8];
    unsigned int recj[8];
#pragma unroll
    for (int j = 0; j < 8; ++j) {
        const int e = base + j * 256 + t;
        bj[j] = -1;
        if (e < E) {
            const int s = eidx[e];
            const int d = eidx[E + e];
            bj[j] = d >> 8;
            recj[j] = ((unsigned)(d & 255) << 24) | (unsigned)s;
            rj[j] = atomicAdd(&lh[bj[j]], 1);
        }
    }
    __syncthreads();
    const int c = lh[t];
    if (c) lb[t] = atomicAdd(&binCursor[t], c);
    __syncthreads();
#pragma unroll
    for (int j = 0; j < 8; ++j) {
        if (bj[j] >= 0) binned[lb[bj[j]] + rj[j]] = recj[j];
    }
}

__global__ __launch_bounds__(256) void k_place(const unsigned int* __restrict__ binned,
                                               const int* __restrict__ binOffs,
                                               int* __restrict__ offs,
                                               int* __restrict__ src_s,
                                               int N, int E) {
    __shared__ int cnt[256];
    __shared__ int ts[256];
    __shared__ int cur[256];
    const int b = blockIdx.x;
    const int t = threadIdx.x;
    const int node0 = b * 256;
    const int r0 = binOffs[b], r1 = binOffs[b + 1];
    cnt[t] = 0;
    __syncthreads();
    for (int i = r0 + t; i < r1; i += 256)
        atomicAdd(&cnt[binned[i] >> 24], 1);
    __syncthreads();
    const int v = cnt[t];
    ts[t] = v;
    __syncthreads();
    for (int o = 1; o < 256; o <<= 1) {
        int u = (t >= o) ? ts[t - o] : 0;
        __syncthreads();
        ts[t] += u;
        __syncthreads();
    }
    const int excl = r0 + ts[t] - v;
    if (node0 + t < N) offs[node0 + t] = excl;
    cur[t] = excl;
    __syncthreads();
    for (int i = r0 + t; i < r1; i += 256) {
        const unsigned int rec = binned[i];
        const int pos = atomicAdd(&cur[rec >> 24], 1);
        src_s[pos] = (int)(rec & 0xFFFFFFu);
    }
    if (b == 0 && t == 0) offs[N] = E;
}

// ---------------------------------------------------------------------------
// K4: fused attention + online softmax + aggregation. One wave per node,
// 8 edges/iter, 8-lane group dots (f16 v_dot2, 256B/edge gather).
// Lean common path: per-group denominator partial (1 exp/lane, 3 shfl, no
// wave broadcasts, no rescale). Rare path (ballot, a > m-28): exact max
// rescale + denominator + xl gather when w > 1e-12. Denominator is exact
// (every edge's exp accumulated); only xl terms with w*|xl|/denom below
// fp32 ulp are skipped.
// ---------------------------------------------------------------------------
__global__ __launch_bounds__(256) void k_agg(const unsigned int* __restrict__ xlh,
                                             const unsigned int* __restrict__ embh,
                                             const int* __restrict__ src_s,
                                             const int* __restrict__ offs,
                                             const float* __restrict__ bias,
                                             float* __restrict__ out, int N) {
    const int node = (int)((blockIdx.x * (size_t)blockDim.x + threadIdx.x) >> 6);
    const int lane = threadIdx.x & 63;
    if (node >= N) return;
    const int g = lane >> 3;        // edge slot 0..7
    const int sl = lane & 7;        // sub-lane within 8-group
    const int s0 = offs[node], s1 = offs[node + 1];

    const uint4* erow = (const uint4*)(embh + (size_t)node * (C / 2));
    const uint4 e0 = erow[sl * 2], e1 = erow[sl * 2 + 1];

    // self-loop logit = ||emb[node]||^2 (identical in all lanes after reduce)
    float p = 0.0f;
    p = dot2acc(e0.x, e0.x, p); p = dot2acc(e0.y, e0.y, p);
    p = dot2acc(e0.z, e0.z, p); p = dot2acc(e0.w, e0.w, p);
    p = dot2acc(e1.x, e1.x, p); p = dot2acc(e1.y, e1.y, p);
    p = dot2acc(e1.z, e1.z, p); p = dot2acc(e1.w, e1.w, p);
    p += __shfl_xor(p, 4); p += __shfl_xor(p, 2); p += __shfl_xor(p, 1);

    float m = p;          // running max (self included)
    float wself = 1.0f;   // exp(self - m)
    float dex = 0.0f;     // rare-path denominator (wave-uniform)
    float dpart = 0.0f;   // per-group denominator partial (uniform in group)
    const unsigned int xw = xlh[(size_t)node * (C / 2) + lane];
    float2 acc = {h2f_lo(xw), h2f_hi(xw)};   // wself * xl[node]

    for (int base = s0; base < s1; base += 8) {
        int mys = -1;
        if (lane < 8 && base + lane < s1) mys = src_s[base + lane];
        const int sg = __shfl(mys, g);
        const int sa = (sg >= 0) ? sg : node;

        // group dot: alpha_g = emb[node] . emb[src_g]
        const uint4* vrow = (const uint4*)(embh + (size_t)sa * (C / 2));
        const uint4 v0 = vrow[sl * 2], v1 = vrow[sl * 2 + 1];
        float a = 0.0f;
        a = dot2acc(e0.x, v0.x, a); a = dot2acc(e0.y, v0.y, a);
        a = dot2acc(e0.z, v0.z, a); a = dot2acc(e0.w, v0.w, a);
        a = dot2acc(e1.x, v1.x, a); a = dot2acc(e1.y, v1.y, a);
        a = dot2acc(e1.z, v1.z, a); a = dot2acc(e1.w, v1.w, a);
        a += __shfl_xor(a, 4); a += __shfl_xor(a, 2); a += __shfl_xor(a, 1);

        const bool valid = sg >= 0;
        const bool hot = valid && (a > m - 28.0f);   // may affect max or output
        if (__any(hot)) {
            const unsigned long long bal = __ballot(hot);
#pragma unroll 1
            for (int j = 0; j < 8; ++j) {
                if (!((bal >> (j * 8)) & 1ULL)) continue;
                const float aj = __shfl(a, j * 8);
                const int sj = __shfl(mys, j);
                if (aj > m) {            // wave-uniform rescale
                    const float cs = __expf(m - aj);
                    dpart *= cs; dex *= cs; wself *= cs;
                    acc.x *= cs; acc.y *= cs;
                    m = aj;
                }
                const float w = __expf(aj - m);
                dex += w;
                if (w > 1e-12f) {
                    const unsigned int u = xlh[(size_t)sj * (C / 2) + lane];
                    acc.x = fmaf(w, h2f_lo(u), acc.x);
                    acc.y = fmaf(w, h2f_hi(u), acc.y);
                }
            }
        }
        // cold groups: exact denominator contribution, no gather
        dpart += (valid && !hot) ? __expf(a - m) : 0.0f;
    }

    // sum the 8 per-group partials (lanes within a group hold identical dpart)
    float dg = dpart;
    dg += __shfl_xor(dg, 8); dg += __shfl_xor(dg, 16); dg += __shfl_xor(dg, 32);
    const float dtot = wself + dex + dg;
    const float inv = 1.0f / (dtot + 1e-16f);
    const int c = lane * 2;
    float2 o2;
    o2.x = fmaf(acc.x, inv, bias[c]);
    o2.y = fmaf(acc.y, inv, bias[c + 1]);
    ((float2*)(out + (size_t)node * C))[lane] = o2;
}

// ---------------------------------------------------------------------------
// K5: BN stats — grid-stride float4; fixed channel quad per thread.
// ---------------------------------------------------------------------------
__global__ __launch_bounds__(256) void k_bnstats(const float* __restrict__ out,
                                                 float* __restrict__ ssum,
                                                 float* __restrict__ ssq, int N) {
    const int tid = threadIdx.x;
    const int total4 = N * (C / 4);
    const int stride = gridDim.x * 256;          // multiple of 32
    float4 s4 = {0, 0, 0, 0}, q4 = {0, 0, 0, 0};
    for (int i = blockIdx.x * 256 + tid; i < total4; i += stride) {
        float4 v = ((const float4*)out)[i];
        s4.x += v.x; s4.y += v.y; s4.z += v.z; s4.w += v.w;
        q4.x = fmaf(v.x, v.x, q4.x); q4.y = fmaf(v.y, v.y, q4.y);
        q4.z = fmaf(v.z, v.z, q4.z); q4.w = fmaf(v.w, v.w, q4.w);
    }
    __shared__ float4 lsum[256];
    __shared__ float4 lsq[256];
    lsum[tid] = s4; lsq[tid] = q4;
    __syncthreads();
    if (tid < 32) {
        float4 S = lsum[tid], Q = lsq[tid];
#pragma unroll
        for (int j = 1; j < 8; ++j) {
            float4 a = lsum[tid + 32 * j], b = lsq[tid + 32 * j];
            S.x += a.x; S.y += a.y; S.z += a.z; S.w += a.w;
            Q.x += b.x; Q.y += b.y; Q.z += b.z; Q.w += b.w;
        }
        const int c = tid * 4;
        atomicAdd(&ssum[c], S.x);     atomicAdd(&ssum[c + 1], S.y);
        atomicAdd(&ssum[c + 2], S.z); atomicAdd(&ssum[c + 3], S.w);
        atomicAdd(&ssq[c], Q.x);      atomicAdd(&ssq[c + 1], Q.y);
        atomicAdd(&ssq[c + 2], Q.z);  atomicAdd(&ssq[c + 3], Q.w);
    }
}

// ---------------------------------------------------------------------------
// K6: in-place BN apply (training-mode batch stats, biased var) + ReLU
// ---------------------------------------------------------------------------
__global__ __launch_bounds__(256) void k_bnapply(float* __restrict__ out,
                                                 const float* __restrict__ ssum,
                                                 const float* __restrict__ ssq,
                                                 const float* __restrict__ gamma,
                                                 const float* __restrict__ beta,
                                                 int N) {
    const int idx = blockIdx.x * blockDim.x + threadIdx.x;   // float4 index
    const int total = N * (C / 4);
    if (idx >= total) return;
    const int c = (idx * 4) & 127;
    float4 v = ((const float4*)out)[idx];
    const float invN = 1.0f / (float)N;
    float r[4] = {v.x, v.y, v.z, v.w};
#pragma unroll
    for (int j = 0; j < 4; ++j) {
        float mu = ssum[c + j] * invN;
        float var = fmaf(-mu, mu, ssq[c + j] * invN);
        var = fmaxf(var, 0.0f);
        float sc = gamma[c + j] / sqrtf(var + 1e-5f);
        float val = fmaf(r[j] - mu, sc, beta[c + j]);
        r[j] = fmaxf(val, 0.0f);
    }
    float4 o = {r[0], r[1], r[2], r[3]};
    ((float4*)out)[idx] = o;
}

// ---------------------------------------------------------------------------
extern "C" void kernel_launch(void* const* d_in, const int* in_sizes, int n_in,
                              void* d_out, int out_size, void* d_ws, size_t ws_size,
                              hipStream_t stream) {
    const float* x     = (const float*)d_in[0];
    const int*   eidx  = (const int*)d_in[1];   // [2][E]
    const float* emb   = (const float*)d_in[2];
    const float* W     = (const float*)d_in[3];
    const float* bias  = (const float*)d_in[4];
    const float* gamma = (const float*)d_in[5];
    const float* beta  = (const float*)d_in[6];
    const int N = in_sizes[0] / C;
    const int E = in_sizes[1] / 2;
    float* out = (float*)d_out;

    char* ws = (char*)d_ws;
    size_t off = 0;
    auto alloc = [&](size_t bytes) -> void* {
        void* p = ws + off;
        off = (off + bytes + 255) & ~(size_t)255;
        return p;
    };
    unsigned short* xlh  = (unsigned short*)alloc((size_t)N * C * 2);
    unsigned int*   embh = (unsigned int*)  alloc((size_t)N * C * 2);
    unsigned int*   wh   = (unsigned int*)  alloc((size_t)C * C * 2);
    int*   src_s    = (int*)  alloc((size_t)E * 4);
    unsigned int* binned = (unsigned int*)alloc((size_t)E * 4);
    int*   offs     = (int*)  alloc((size_t)(N + 1) * 4);
    int*   binOffs  = (int*)  alloc(257 * 4);
    int*   binCur   = (int*)  alloc(256 * 4);
    // contiguous zero-init region: binCounts + ssum + ssq
    char*  zbase    = (char*)alloc(0);
    int*   binCounts= (int*)  alloc(256 * 4);
    float* ssum     = (float*)alloc(C * 4);
    float* ssq      = (float*)alloc(C * 4);
    size_t zbytes   = (char*)ws + off - zbase;

    const int NB = (N + 255) / 256;              // 196 bins (<= 255)
    const int nEdgeBlocks = (E + 2047) / 2048;   // 391
    const int embTot8 = N * (C / 8);
    const int wTot8   = C * (C / 8);

    hipMemsetAsync(zbase, 0, zbytes, stream);

    k_cast   <<<(embTot8 + wTot8 + 255) / 256, 256, 0, stream>>>(
                 emb, embh, W, wh, embTot8, wTot8);
    k_gemm   <<<(N + 63) / 64,   256, 0, stream>>>(x, (const uint4*)wh, xlh, N);
    k_binhist<<<nEdgeBlocks,     256, 0, stream>>>(eidx, binCounts, E);
    k_binscan<<<1,               256, 0, stream>>>(binCounts, binOffs, binCur, NB);
    k_bin    <<<nEdgeBlocks,     256, 0, stream>>>(eidx, binCur, binned, E);
    k_place  <<<NB,              256, 0, stream>>>(binned, binOffs, offs, src_s, N, E);
    k_agg    <<<(int)(((size_t)N * 64 + 255) / 256), 256, 0, stream>>>(
                 (const unsigned int*)xlh, embh, src_s, offs, bias, out, N);
    k_bnstats<<<256,             256, 0, stream>>>(out, ssum, ssq, N);
    k_bnapply<<<(N * (C / 4) + 255) / 256, 256, 0, stream>>>(out, ssum, ssq, gamma, beta, N);
}